// Round 5
// baseline (442.979 us; speedup 1.0000x reference)
//
#include <hip/hip_runtime.h>

#define N_FEATS 256
#define HIDDEN  128
#define N_CLASS 64
#define BATCH   1024
#define K0      25
#define K1      10
#define N_HIST  5
#define KDIM    512

typedef unsigned short u16;

// Dual-dtype float load. Address derived from flag BEFORE any load, so even a
// compiler-speculated wrong-width load stays within the buffer.
static __device__ __forceinline__ float loadF(const void* p, long long i, int fbf) {
    const char* cp = (const char*)p + (fbf ? (i << 1) : (i << 2));
    if (fbf) {
        union { unsigned int u; float f; } v;
        v.u = ((unsigned int)(*(const u16*)cp)) << 16;
        return v.f;
    }
    return *(const float*)cp;
}

// Dual-width int load: little-endian low word == value for both int32/int64.
static __device__ __forceinline__ int loadI(const void* p, long long i, int f64) {
    const char* cp = (const char*)p + (f64 ? (i << 3) : (i << 2));
    return *(const int*)cp;
}

// ---------------------------------------------------------------------------
// Monolithic fused GraphSAGE forward. One block (256 thr) per batch row.
// Phase A: detect dtypes. Phase B: gather 11 X rows [self(256)|mean25(256)]
// into LDS. Phase C: X @ W0 (+b0, relu) via LDS-slabbed VALU dots, 11 rows.
// Phase D: delta/history mean -> hcat[256]. Phase E: hcat @ W1 (+b1, relu).
// Output is fp32 (reference output dtype). No workspace use.
// ---------------------------------------------------------------------------
__global__ __launch_bounds__(256) void k_fused(
        const void* __restrict__ feats,
        const void* __restrict__ history,
        const void* __restrict__ W0,
        const void* __restrict__ b0,
        const void* __restrict__ W1,
        const void* __restrict__ b1,
        const void* __restrict__ nodes,
        const void* __restrict__ neighs0,
        const void* __restrict__ neighs1,
        const void* __restrict__ neighs0_nb,
        const void* __restrict__ h_nodes,
        float* __restrict__ out) {
    __shared__ float W0s[32][128];     // 16 KB   k-slab of W0, fp32
    __shared__ float Xs[11][KDIM];     // 22.5 KB 11 layer-0 input rows
    __shared__ float hcat[2 * HIDDEN]; // 1 KB
    __shared__ float red[256];         // 1 KB
    __shared__ int ibuf[K0 + 1];
    __shared__ int sflags[2];

    const int tid = threadIdx.x;
    const int b = blockIdx.x;

    // ---- Phase A: dtype detection (thread 0, deterministic per call)
    if (tid == 0) {
        const int* ip = (const int*)nodes;      // int64 iff odd words all zero
        int f = 1;
        for (int i = 0; i < 8; ++i)
            if (ip[2 * i + 1] != 0) f = 0;
        sflags[0] = f;
        const u16* qp = (const u16*)feats;      // bf16 iff even u16s have sane exps
        int cnt = 0;
        for (int i = 0; i < 64; ++i) {
            int e = (qp[2 * i] >> 7) & 0xFF;
            if (e >= 90 && e <= 134) cnt++;
        }
        sflags[1] = (cnt >= 40) ? 1 : 0;
    }
    __syncthreads();
    const int f64 = sflags[0];
    const int fbf = sflags[1];

    // ---- Phase B: gather + mean, 11 rows. Row 0: self=nodes[b], nb=neighs0[b].
    // Row r>0: rr=b*K1+(r-1), self=neighs1[rr], nb=neighs0_nb[rr].
    for (int r = 0; r < 11; ++r) {
        __syncthreads();   // protect ibuf reuse across iterations
        if (tid < K0) {
            long long nbo = (r == 0) ? ((long long)b * K0)
                                     : ((long long)(b * K1 + (r - 1)) * K0);
            const void* nbp = (r == 0) ? neighs0 : neighs0_nb;
            ibuf[tid] = loadI(nbp, nbo + tid, f64);
        } else if (tid == K0) {
            ibuf[K0] = (r == 0) ? loadI(nodes, b, f64)
                                : loadI(neighs1, b * K1 + (r - 1), f64);
        }
        __syncthreads();
        int sidx = ibuf[K0];
        Xs[r][tid] = loadF(feats, (long long)sidx * N_FEATS + tid, fbf);
        float s = 0.f;
#pragma unroll
        for (int k = 0; k < K0; ++k)
            s += loadF(feats, (long long)ibuf[k] * N_FEATS + tid, fbf);
        Xs[r][N_FEATS + tid] = s * (1.0f / (float)K0);
    }
    __syncthreads();

    // ---- Phase C: acc[r] = partial dot for col c over this thread's k-range.
    // 2 threads per col: c = tid&127, ph = tid>>7 covers 16 of each 32-k slab.
    const int c = tid & 127;
    const int ph = tid >> 7;
    float acc[11];
#pragma unroll
    for (int r = 0; r < 11; ++r) acc[r] = 0.f;

    for (int s = 0; s < 16; ++s) {
        __syncthreads();   // protect W0s reuse
#pragma unroll
        for (int i = 0; i < 16; ++i) {
            int idx = tid + 256 * i;
            int k = idx >> 7, cc = idx & 127;
            W0s[k][cc] = loadF(W0, (long long)(32 * s + k) * HIDDEN + cc, fbf);
        }
        __syncthreads();
        const int kb = 32 * s + 16 * ph;
#pragma unroll
        for (int r = 0; r < 11; ++r) {
            float a = 0.f;
#pragma unroll
            for (int j = 0; j < 16; ++j)
                a += Xs[r][kb + j] * W0s[16 * ph + j][c];
            acc[r] += a;
        }
    }

    // ---- Phase D: combine halves, bias+relu, delta/history accumulation.
    float S = 0.f;                                   // threads tid<128 own col=tid
    float b0v = (tid < 128) ? loadF(b0, tid, fbf) : 0.f;
    for (int r = 0; r < 11; ++r) {
        __syncthreads();   // protect red reuse
        red[tid] = acc[r];
        __syncthreads();
        if (tid < 128) {
            float h = red[tid] + red[tid + 128] + b0v;
            h = h > 0.f ? h : 0.f;
            if (r == 0) {
                hcat[tid] = h;                       // h1
            } else {
                int n1 = loadI(neighs1, b * K1 + (r - 1), f64);
                float hist = loadF(history, (long long)n1 * HIDDEN + tid, fbf);
                S += 0.5f * (h - hist);              // (N_HIST/K1) = 0.5
            }
        }
    }
    if (tid < 128) {
#pragma unroll
        for (int u = 0; u < N_HIST; ++u) {
            int hn = loadI(h_nodes, b * N_HIST + u, f64);
            S += loadF(history, (long long)hn * HIDDEN + tid, fbf);
        }
        hcat[HIDDEN + tid] = S * (1.0f / 15.0f);
    }
    __syncthreads();

    // ---- Phase E: out[b][n] = relu(b1[n] + hcat . W1[:,n]), fp32 store.
    const int n = tid & 63;
    const int seg = tid >> 6;
    float p = 0.f;
#pragma unroll 8
    for (int i = seg * 64; i < seg * 64 + 64; ++i)
        p += hcat[i] * loadF(W1, (long long)i * N_CLASS + n, fbf);
    red[tid] = p;
    __syncthreads();
    if (tid < 64) {
        float a = red[tid] + red[tid + 64] + red[tid + 128] + red[tid + 192]
                + loadF(b1, tid, fbf);
        a = a > 0.f ? a : 0.f;
        out[(long long)b * N_CLASS + tid] = a;   // fp32 output (the R3/R4 fix)
    }
}

// ---------------------------------------------------------------------------
extern "C" void kernel_launch(void* const* d_in, const int* in_sizes, int n_in,
                              void* d_out, int out_size, void* d_ws, size_t ws_size,
                              hipStream_t stream) {
    (void)d_ws; (void)ws_size; (void)out_size;
    // Positional binding primary (harness doc: dict order); size-based rebind
    // only when the positional size disagrees and a unique match exists.
    const long long want[11] = {25600000, 12800000, 65536, 128, 16384, 64,
                                1024, 25600, 10240, 256000, 5120};
    const void* bp[11];
    for (int j = 0; j < 11; ++j) bp[j] = d_in[j < n_in ? j : 0];
    for (int j = 0; j < 11; ++j) {
        if (j < n_in && (long long)in_sizes[j] == want[j]) continue;
        for (int i = 0; i < n_in; ++i)
            if ((long long)in_sizes[i] == want[j]) { bp[j] = d_in[i]; break; }
    }

    k_fused<<<BATCH, 256, 0, stream>>>(
        bp[0], bp[1], bp[2], bp[3], bp[4], bp[5],
        bp[6], bp[7], bp[8], bp[9], bp[10],
        (float*)d_out);
}

// Round 6
// 222.813 us; speedup vs baseline: 1.9881x; 1.9881x over previous
//
#include <hip/hip_runtime.h>

#define N_FEATS 256
#define HIDDEN  128
#define N_CLASS 64
#define BATCH   1024
#define K0      25
#define K1      10
#define N_HIST  5
#define M_TOTAL (BATCH + BATCH * K1)   // 11264 layer-0 rows
#define KDIM    512

typedef unsigned short u16;
typedef short bf16x8 __attribute__((ext_vector_type(8)));
typedef float f32x4 __attribute__((ext_vector_type(4)));

static __device__ __forceinline__ u16 f2bf(float f) {
    union { float f; unsigned int i; } v;
    v.f = f;
    unsigned int x = v.i;
    x += ((x >> 16) & 1u) + 0x7FFFu;   // round-to-nearest-even
    return (u16)(x >> 16);
}
static __device__ __forceinline__ unsigned int pack2(float lo, float hi) {
    return (unsigned int)f2bf(lo) | ((unsigned int)f2bf(hi) << 16);
}
// Dual-width int load: little-endian low word == value for both int32/int64.
static __device__ __forceinline__ int loadI(const void* p, long long i, int f64) {
    const char* cp = (const char*)p + (f64 ? (i << 3) : (i << 2));
    return *(const int*)cp;
}

// ---------------------------------------------------------------------------
// int64-vs-int32 detection (odd int32 slots of nodes all zero => int64).
// ---------------------------------------------------------------------------
__global__ void k_detect(const void* __restrict__ nodes, int* __restrict__ flag) {
    if (threadIdx.x == 0 && blockIdx.x == 0) {
        const int* p = (const int*)nodes;
        int f = 1;
        for (int i = 0; i < 8; ++i)
            if (p[2 * i + 1] != 0) f = 0;
        *flag = f;
    }
}

// ---------------------------------------------------------------------------
// W0 fp32 (512x128) -> bf16 W0T (128x512): column n of W0 becomes row n,
// so GEMM B-frags are contiguous 16B loads.
// ---------------------------------------------------------------------------
__global__ void k_transpose_w0(const float* __restrict__ W0, u16* __restrict__ W0T) {
    __shared__ u16 tile[32][33];
    int tx = threadIdx.x;            // 0..31
    int ty = threadIdx.y;            // 0..7
    int k0 = blockIdx.x * 32;        // K tile (16 blocks)
    int n0 = blockIdx.y * 32;        // N tile (4 blocks)
#pragma unroll
    for (int i = 0; i < 32; i += 8)
        tile[ty + i][tx] = f2bf(W0[(size_t)(k0 + ty + i) * HIDDEN + n0 + tx]);
    __syncthreads();
#pragma unroll
    for (int i = 0; i < 32; i += 8)
        W0T[(size_t)(n0 + ty + i) * KDIM + k0 + tx] = tile[tx][ty + i];
}

// ---------------------------------------------------------------------------
// Fused layer-0: gather + mean + MFMA GEMM + bias + ReLU.
// One 512-thread block (8 waves) per 16-row M-tile.
// Phase 1: wave wv gathers rows {2wv, 2wv+1}: X = [self(256)|mean25(256)],
//          float4 16B/lane (one wave = one full 1KB feat row per load), ->bf16 LDS.
// Phase 2: wave wv computes n-tile wv (cols 16wv..16wv+15) over all 16 rows.
// Verified layouts (learn_hip m89/m91):
//   A[m=lane&15][k=q*8+j], B[k=q*8+j][n=lane&15], D[row=q*4+r][col=lane&15].
// ---------------------------------------------------------------------------
__global__ __launch_bounds__(512) void k_layer0(
        const float* __restrict__ feats,
        const void* __restrict__ nodes,
        const void* __restrict__ neighs0,
        const void* __restrict__ neighs1,
        const void* __restrict__ neighs0_nb,
        const u16* __restrict__ W0T,
        const float* __restrict__ b0,
        float* __restrict__ H,
        const int* __restrict__ flag) {
    __shared__ u16 Xs[16][KDIM + 8];   // 16.6 KB; +8 u16 pad, rows 16B-aligned
    const int f64 = *flag;
    int wv = threadIdx.x >> 6;         // 0..7
    int lane = threadIdx.x & 63;
    int row0 = blockIdx.x * 16;
    int d = lane * 4;                  // this lane's 4 feature dims

    // ---- Phase 1: gather + mean (wave wv owns local rows 2wv, 2wv+1)
#pragma unroll
    for (int i = 0; i < 2; ++i) {
        int lr = wv * 2 + i;
        int g = row0 + lr;
        int selfIdx;
        const void* nbp;
        long long nbo;
        if (g < BATCH) {
            selfIdx = loadI(nodes, g, f64);
            nbp = neighs0; nbo = (long long)g * K0;
        } else {
            int rr = g - BATCH;
            selfIdx = loadI(neighs1, rr, f64);
            nbp = neighs0_nb; nbo = (long long)rr * K0;
        }
        int idx[K0];
#pragma unroll
        for (int k = 0; k < K0; ++k) idx[k] = loadI(nbp, nbo + k, f64);

        float4 sv = *(const float4*)(feats + (size_t)selfIdx * N_FEATS + d);
        float a0 = 0.f, a1 = 0.f, a2 = 0.f, a3 = 0.f;
#pragma unroll
        for (int k = 0; k < K0; ++k) {
            float4 v = *(const float4*)(feats + (size_t)idx[k] * N_FEATS + d);
            a0 += v.x; a1 += v.y; a2 += v.z; a3 += v.w;
        }
        const float inv = 1.0f / (float)K0;
        uint2 spk, mpk;
        spk.x = pack2(sv.x, sv.y);
        spk.y = pack2(sv.z, sv.w);
        mpk.x = pack2(a0 * inv, a1 * inv);
        mpk.y = pack2(a2 * inv, a3 * inv);
        *(uint2*)&Xs[lr][d] = spk;
        *(uint2*)&Xs[lr][N_FEATS + d] = mpk;
    }
    __syncthreads();

    // ---- Phase 2: MFMA. wave wv -> n-tile wv (16 cols), all 16 rows.
    int m = lane & 15;
    int q = lane >> 4;
    f32x4 acc = (f32x4){0.f, 0.f, 0.f, 0.f};
    const u16* bbase = W0T + (size_t)(wv * 16 + m) * KDIM + q * 8;
#pragma unroll
    for (int k0 = 0; k0 < KDIM; k0 += 32) {
        bf16x8 af = *(const bf16x8*)&Xs[m][k0 + q * 8];
        bf16x8 bf = *(const bf16x8*)(bbase + k0);
        acc = __builtin_amdgcn_mfma_f32_16x16x32_bf16(af, bf, acc, 0, 0, 0);
    }
    int col = wv * 16 + m;
    float bias = b0[col];
#pragma unroll
    for (int r = 0; r < 4; ++r) {
        float y = acc[r] + bias;
        y = y > 0.f ? y : 0.f;
        H[(size_t)(row0 + q * 4 + r) * HIDDEN + col] = y;
    }
}

// ---------------------------------------------------------------------------
// Final layer: one 256-thread block per batch row.
// Phase D (t-split over halves): hcat = [h1(128) |
//   (sum_t 0.5*(H_orig - hist[n1]) + sum_u hist[h_nodes]) / 15]
// Phase E: out[b][n] = relu(b1[n] + hcat . W1[:,n]), 4-segment LDS reduce.
// ---------------------------------------------------------------------------
__global__ __launch_bounds__(256) void k_final(
        const float* __restrict__ H,
        const float* __restrict__ history,
        const void* __restrict__ neighs1,
        const void* __restrict__ h_nodes,
        const float* __restrict__ W1,
        const float* __restrict__ b1,
        float* __restrict__ out,
        const int* __restrict__ flag) {
    __shared__ float hcat[2 * HIDDEN];
    __shared__ float red[256];
    const int f64 = *flag;
    const int tid = threadIdx.x;
    const int b = blockIdx.x;
    const int j = tid & 127;
    const int half = tid >> 7;

    // ---- Phase D: half 0 does t=0..4 (+h1), half 1 does t=5..9 (+history).
    float S = 0.f;
    if (half == 0) hcat[j] = H[(size_t)b * HIDDEN + j];
#pragma unroll
    for (int t = half * 5; t < half * 5 + 5; ++t) {
        float orig = H[(size_t)(BATCH + b * K1 + t) * HIDDEN + j];
        int n1 = loadI(neighs1, b * K1 + t, f64);
        float hist = history[(size_t)n1 * HIDDEN + j];
        S += 0.5f * (orig - hist);                  // (N_HIST/K1) = 0.5
    }
    if (half == 1) {
#pragma unroll
        for (int u = 0; u < N_HIST; ++u) {
            int hn = loadI(h_nodes, b * N_HIST + u, f64);
            S += history[(size_t)hn * HIDDEN + j];
        }
    }
    red[tid] = S;
    __syncthreads();
    if (half == 0)
        hcat[HIDDEN + j] = (red[j] + red[HIDDEN + j]) * (1.0f / 15.0f);
    __syncthreads();

    // ---- Phase E: 4 threads per class column, 64-length partial dots.
    const int n = tid & 63;
    const int seg = tid >> 6;
    float p = 0.f;
#pragma unroll 8
    for (int i = seg * 64; i < seg * 64 + 64; ++i)
        p += hcat[i] * W1[(size_t)i * N_CLASS + n];
    red[tid] = p;
    __syncthreads();
    if (tid < 64) {
        float a = red[tid] + red[tid + 64] + red[tid + 128] + red[tid + 192]
                + b1[tid];
        a = a > 0.f ? a : 0.f;
        out[(size_t)b * N_CLASS + tid] = a;
    }
}

// ===========================================================================
// Fallback: R5's known-good monolithic kernel (used only if ws too small).
// ===========================================================================
static __device__ __forceinline__ float loadF_m(const void* p, long long i, int fbf) {
    const char* cp = (const char*)p + (fbf ? (i << 1) : (i << 2));
    if (fbf) {
        union { unsigned int u; float f; } v;
        v.u = ((unsigned int)(*(const u16*)cp)) << 16;
        return v.f;
    }
    return *(const float*)cp;
}

__global__ __launch_bounds__(256) void k_fused(
        const void* __restrict__ feats,
        const void* __restrict__ history,
        const void* __restrict__ W0,
        const void* __restrict__ b0,
        const void* __restrict__ W1,
        const void* __restrict__ b1,
        const void* __restrict__ nodes,
        const void* __restrict__ neighs0,
        const void* __restrict__ neighs1,
        const void* __restrict__ neighs0_nb,
        const void* __restrict__ h_nodes,
        float* __restrict__ out) {
    __shared__ float W0s[32][128];
    __shared__ float Xs[11][KDIM];
    __shared__ float hcat[2 * HIDDEN];
    __shared__ float red[256];
    __shared__ int ibuf[K0 + 1];
    __shared__ int sflags[2];

    const int tid = threadIdx.x;
    const int b = blockIdx.x;

    if (tid == 0) {
        const int* ip = (const int*)nodes;
        int f = 1;
        for (int i = 0; i < 8; ++i)
            if (ip[2 * i + 1] != 0) f = 0;
        sflags[0] = f;
        const u16* qp = (const u16*)feats;
        int cnt = 0;
        for (int i = 0; i < 64; ++i) {
            int e = (qp[2 * i] >> 7) & 0xFF;
            if (e >= 90 && e <= 134) cnt++;
        }
        sflags[1] = (cnt >= 40) ? 1 : 0;
    }
    __syncthreads();
    const int f64 = sflags[0];
    const int fbf = sflags[1];

    for (int r = 0; r < 11; ++r) {
        __syncthreads();
        if (tid < K0) {
            long long nbo = (r == 0) ? ((long long)b * K0)
                                     : ((long long)(b * K1 + (r - 1)) * K0);
            const void* nbp = (r == 0) ? neighs0 : neighs0_nb;
            ibuf[tid] = loadI(nbp, nbo + tid, f64);
        } else if (tid == K0) {
            ibuf[K0] = (r == 0) ? loadI(nodes, b, f64)
                                : loadI(neighs1, b * K1 + (r - 1), f64);
        }
        __syncthreads();
        int sidx = ibuf[K0];
        Xs[r][tid] = loadF_m(feats, (long long)sidx * N_FEATS + tid, fbf);
        float s = 0.f;
#pragma unroll
        for (int k = 0; k < K0; ++k)
            s += loadF_m(feats, (long long)ibuf[k] * N_FEATS + tid, fbf);
        Xs[r][N_FEATS + tid] = s * (1.0f / (float)K0);
    }
    __syncthreads();

    const int c = tid & 127;
    const int ph = tid >> 7;
    float acc[11];
#pragma unroll
    for (int r = 0; r < 11; ++r) acc[r] = 0.f;

    for (int s = 0; s < 16; ++s) {
        __syncthreads();
#pragma unroll
        for (int i = 0; i < 16; ++i) {
            int idx = tid + 256 * i;
            int k = idx >> 7, cc = idx & 127;
            W0s[k][cc] = loadF_m(W0, (long long)(32 * s + k) * HIDDEN + cc, fbf);
        }
        __syncthreads();
        const int kb = 32 * s + 16 * ph;
#pragma unroll
        for (int r = 0; r < 11; ++r) {
            float a = 0.f;
#pragma unroll
            for (int j = 0; j < 16; ++j)
                a += Xs[r][kb + j] * W0s[16 * ph + j][c];
            acc[r] += a;
        }
    }

    float S = 0.f;
    float b0v = (tid < 128) ? loadF_m(b0, tid, fbf) : 0.f;
    for (int r = 0; r < 11; ++r) {
        __syncthreads();
        red[tid] = acc[r];
        __syncthreads();
        if (tid < 128) {
            float h = red[tid] + red[tid + 128] + b0v;
            h = h > 0.f ? h : 0.f;
            if (r == 0) {
                hcat[tid] = h;
            } else {
                int n1 = loadI(neighs1, b * K1 + (r - 1), f64);
                float hist = loadF_m(history, (long long)n1 * HIDDEN + tid, fbf);
                S += 0.5f * (h - hist);
            }
        }
    }
    if (tid < 128) {
#pragma unroll
        for (int u = 0; u < N_HIST; ++u) {
            int hn = loadI(h_nodes, b * N_HIST + u, f64);
            S += loadF_m(history, (long long)hn * HIDDEN + tid, fbf);
        }
        hcat[HIDDEN + tid] = S * (1.0f / 15.0f);
    }
    __syncthreads();

    const int n = tid & 63;
    const int seg = tid >> 6;
    float p = 0.f;
#pragma unroll 8
    for (int i = seg * 64; i < seg * 64 + 64; ++i)
        p += hcat[i] * loadF_m(W1, (long long)i * N_CLASS + n, fbf);
    red[tid] = p;
    __syncthreads();
    if (tid < 64) {
        float a = red[tid] + red[tid + 64] + red[tid + 128] + red[tid + 192]
                + loadF_m(b1, tid, fbf);
        a = a > 0.f ? a : 0.f;
        out[(long long)b * N_CLASS + tid] = a;
    }
}

// ---------------------------------------------------------------------------
extern "C" void kernel_launch(void* const* d_in, const int* in_sizes, int n_in,
                              void* d_out, int out_size, void* d_ws, size_t ws_size,
                              hipStream_t stream) {
    (void)out_size;
    const long long want[11] = {25600000, 12800000, 65536, 128, 16384, 64,
                                1024, 25600, 10240, 256000, 5120};
    const void* bp[11];
    for (int j = 0; j < 11; ++j) bp[j] = d_in[j < n_in ? j : 0];
    for (int j = 0; j < 11; ++j) {
        if (j < n_in && (long long)in_sizes[j] == want[j]) continue;
        for (int i = 0; i < n_in; ++i)
            if ((long long)in_sizes[i] == want[j]) { bp[j] = d_in[i]; break; }
    }

    // ws layout: W0T bf16 (131072 B) | H fp32 (5767168 B) | flag (4 B)
    const size_t WS_NEED = 131072 + 5767168 + 16;
    if (ws_size < WS_NEED) {   // deterministic across calls -> graph-safe
        k_fused<<<BATCH, 256, 0, stream>>>(
            bp[0], bp[1], bp[2], bp[3], bp[4], bp[5],
            bp[6], bp[7], bp[8], bp[9], bp[10], (float*)d_out);
        return;
    }

    char* ws = (char*)d_ws;
    u16* W0T  = (u16*)ws;
    float* H  = (float*)(ws + 131072);
    int* flag = (int*)(ws + 131072 + 5767168);

    k_detect<<<1, 1, 0, stream>>>(bp[6], flag);
    k_transpose_w0<<<dim3(16, 4), dim3(32, 8), 0, stream>>>((const float*)bp[2], W0T);
    k_layer0<<<M_TOTAL / 16, 512, 0, stream>>>(
        (const float*)bp[0], bp[6], bp[7], bp[8], bp[9], W0T,
        (const float*)bp[3], H, flag);
    k_final<<<BATCH, 256, 0, stream>>>(
        H, (const float*)bp[1], bp[8], bp[10],
        (const float*)bp[4], (const float*)bp[5], (float*)d_out, flag);
}